// Round 4
// baseline (1533.529 us; speedup 1.0000x reference)
//
#include <hip/hip_runtime.h>
#include <math.h>

#define PI2F 6.283185307179586f

// B=4 NX=512 NT=128 W=64 M=16 ; BT=512 ; NSIG=32768
// ws (floats): XS[16.7M] | AH half-spectrum (float2)[16.7M f] | X1/hist[16.7M] | smalls

// ---------------- K1a: transpose x[b,n,t,i] -> xs[bt,i,n] ----------------
__global__ __launch_bounds__(256) void k1a_transpose(const float* __restrict__ x,
                                                     float* __restrict__ xs) {
  const int bt = blockIdx.x >> 2, nt4 = blockIdx.x & 3;
  const int b = bt >> 7, t = bt & 127;
  const int n0 = nt4 * 128;
  __shared__ float tile[128 * 66];
  const int tid = threadIdx.x;
  const int i = tid & 63, nq = tid >> 6;
  const float* xb = x + (size_t)b * 4194304 + (size_t)t * 64;
  for (int k = 0; k < 32; k++) {
    int nl = nq + 4 * k;
    tile[nl * 66 + i] = xb[(size_t)(n0 + nl) * 8192 + i];
  }
  __syncthreads();
  float* dst = xs + (size_t)bt * 32768;
  for (int idx = tid; idx < 8192; idx += 256) {
    int ii = idx >> 7, nl = idx & 127;
    dst[ii * 512 + n0 + nl] = tile[nl * 66 + ii];
  }
}

// ---------------- K2: norm (inline) + forward FFT; write half spectrum ----------------
__global__ __launch_bounds__(64) void k2_fft(const float* __restrict__ xs,
                                             float2* __restrict__ alpha,   // [s][256]
                                             float2* __restrict__ a0,
                                             float2* __restrict__ a256,
                                             float2* __restrict__ s1o,
                                             float2* __restrict__ s2o,
                                             const float* __restrict__ grd) {
  __shared__ float2 bufA[512], bufB[512], tw[256];
  const int s = blockIdx.x, tid = threadIdx.x;
  const float dt = grd[1] - grd[0];
  const float Ndt = 512.f * dt;
  for (int m = tid; m < 256; m += 64) {
    float ang = -PI2F * (float)m * (1.f / 512.f);
    float sv, cv; sincosf(ang, &sv, &cv);
    tw[m].x = cv; tw[m].y = sv;
  }
  const float* src = xs + (size_t)s * 512;
  float v[8]; float sm = 0.f, sq = 0.f;
#pragma unroll
  for (int k = 0; k < 8; k++) { v[k] = src[tid + 64 * k]; sm += v[k]; sq += v[k] * v[k]; }
#pragma unroll
  for (int off = 32; off; off >>= 1) { sm += __shfl_down(sm, off); sq += __shfl_down(sq, off); }
  sm = __shfl(sm, 0); sq = __shfl(sq, 0);
  float mu = sm * (1.f / 512.f);
  float var = sq * (1.f / 512.f) - mu * mu;
  float rs = rsqrtf(var + 1e-5f);
#pragma unroll
  for (int k = 0; k < 8; k++) { bufA[tid + 64 * k].x = (v[k] - mu) * rs; bufA[tid + 64 * k].y = 0.f; }
  __syncthreads();
  float2* sp = bufA; float2* dp = bufB;
  int Ns = 1;
  for (int st = 0; st < 9; st++) {
    const int shift = 8 - st;
    for (int jj = 0; jj < 4; jj++) {
      int j = tid + 64 * jj;
      int r = j & (Ns - 1);
      float2 a = sp[j], b = sp[j + 256];
      float2 w = tw[r << shift];
      float wbx = w.x * b.x - w.y * b.y;
      float wby = w.x * b.y + w.y * b.x;
      int id = ((j >> st) << (st + 1)) + r;
      dp[id].x = a.x + wbx; dp[id].y = a.y + wby;
      dp[id + Ns].x = a.x - wbx; dp[id + Ns].y = a.y - wby;
    }
    __syncthreads();
    float2* tp = sp; sp = dp; dp = tp;
    Ns <<= 1;
  }
  float2* dst = alpha + (size_t)s * 256;
  float s1x = 0.f, s1y = 0.f, s2x = 0.f, s2y = 0.f;
  for (int k = tid; k < 512; k += 64) {
    float2 vv = sp[k];
    if (k < 256) dst[k] = vv;
    if (k != 0) {
      int kk = (k < 256) ? k : k - 512;
      float invL = Ndt / (PI2F * (float)kk);
      s1x += vv.y * invL; s1y -= vv.x * invL;
      float invL2 = invL * invL;
      s2x -= vv.x * invL2; s2y -= vv.y * invL2;
    }
  }
#pragma unroll
  for (int off = 32; off; off >>= 1) {
    s1x += __shfl_down(s1x, off); s1y += __shfl_down(s1y, off);
    s2x += __shfl_down(s2x, off); s2y += __shfl_down(s2y, off);
  }
  if (tid == 0) {
    s1o[s].x = s1x; s1o[s].y = s1y;
    s2o[s].x = s2x; s2o[s].y = s2y;
    a0[s] = sp[0];
    a256[s] = sp[256];
  }
}

// ---------------- K3a: R0/R1/R2 complex, P=2ReR1, Q=2ReR2, pole^T ----------------
__global__ __launch_bounds__(64) void k3a_R(const float* __restrict__ pre, const float* __restrict__ pim,
                                            const float* __restrict__ rre, const float* __restrict__ rim,
                                            float2* __restrict__ R0, float2* __restrict__ R1,
                                            float2* __restrict__ R2,
                                            float* __restrict__ Pm, float* __restrict__ Qm,
                                            float* __restrict__ ptr_re, float* __restrict__ ptr_im) {
  const int i = blockIdx.x, o = threadIdx.x;
  float r0x = 0, r0y = 0, r1x = 0, r1y = 0, r2x = 0, r2y = 0;
  for (int m = 0; m < 16; m++) {
    size_t idx = ((size_t)i * 64 + o) * 16 + m;
    float px = pre[idx], py = pim[idx];
    float rx = rre[idx], ry = rim[idx];
    r1x += rx; r1y += ry;
    r2x += rx * px - ry * py; r2y += rx * py + ry * px;
    float inv = 1.f / (px * px + py * py);
    r0x -= (rx * px + ry * py) * inv;
    r0y -= (ry * px - rx * py) * inv;
    ptr_re[((size_t)i * 16 + m) * 64 + o] = px;
    ptr_im[((size_t)i * 16 + m) * 64 + o] = py;
  }
  R0[i * 64 + o].x = r0x; R0[i * 64 + o].y = r0y;
  R1[i * 64 + o].x = r1x; R1[i * 64 + o].y = r1y;
  R2[i * 64 + o].x = r2x; R2[i * 64 + o].y = r2y;
  Pm[i * 64 + o] = 2.f * r1x;
  Qm[i * 64 + o] = 2.f * r2x;
}

// ---------------- K3b: or2[bt,o,m] ----------------
__global__ __launch_bounds__(1024) void k3b_or2(const float* __restrict__ pre, const float* __restrict__ pim,
                                                const float* __restrict__ rre, const float* __restrict__ rim,
                                                const float2* __restrict__ a0, const float2* __restrict__ s1,
                                                const float2* __restrict__ s2, float2* __restrict__ or2) {
  const int bt = blockIdx.x;
  __shared__ float2 A0[64], S1[64], S2[64];
  const int tid = threadIdx.x;
  if (tid < 64) { A0[tid] = a0[bt * 64 + tid]; S1[tid] = s1[bt * 64 + tid]; S2[tid] = s2[bt * 64 + tid]; }
  __syncthreads();
  float ax = 0.f, ay = 0.f;
  for (int i = 0; i < 64; i++) {
    size_t idx = (size_t)i * 1024 + tid;
    float px = pre[idx], py = pim[idx];
    float rx = rre[idx], ry = rim[idx];
    float inv = 1.f / (px * px + py * py);
    float q0x = -(rx * px + ry * py) * inv;
    float q0y = -(ry * px - rx * py) * inv;
    float2 a0v = A0[i], s1v = S1[i], s2v = S2[i];
    float tx = q0x * a0v.x - q0y * a0v.y + rx * s1v.x - ry * s1v.y;
    float ty = q0x * a0v.y + q0y * a0v.x + rx * s1v.y + ry * s1v.x;
    float rpx = rx * px - ry * py, rpy = rx * py + ry * px;
    tx += rpx * s2v.x - rpy * s2v.y;
    ty += rpx * s2v.y + rpy * s2v.x;
    ax -= tx; ay -= ty;
  }
  or2[(size_t)bt * 1024 + tid].x = ax;
  or2[(size_t)bt * 1024 + tid].y = ay;
}

// ---------------- K3c: T0/T1/T2 + or10re + r256 ----------------
__global__ __launch_bounds__(256) void k3c_T(const float2* __restrict__ or2,
                                             const float* __restrict__ ptr_re, const float* __restrict__ ptr_im,
                                             const float2* __restrict__ R0, const float2* __restrict__ R1,
                                             const float2* __restrict__ R2,
                                             const float2* __restrict__ a0, const float2* __restrict__ a256,
                                             float* __restrict__ T0, float* __restrict__ T1,
                                             float* __restrict__ T2,
                                             float* __restrict__ or10re, float* __restrict__ r256o,
                                             const float* __restrict__ grd) {
  const int bt = blockIdx.x * 4 + (threadIdx.x >> 6);
  const int o = threadIdx.x & 63;
  const float dt = grd[1] - grd[0];
  const float invL256 = -(512.f * dt) / (PI2F * 256.f);
  float ox = 0.f;
  float c1x = 0.f, c1y = 0.f, c2x = 0.f, c2y = 0.f;
  for (int i = 0; i < 64; i++) {
    float2 av = a0[bt * 64 + i];
    float2 rv = R0[i * 64 + o];
    ox += av.x * rv.x - av.y * rv.y;
    float2 aw = a256[bt * 64 + i];
    float2 r1v = R1[i * 64 + o], r2v = R2[i * 64 + o];
    c1x += aw.x * r1v.x - aw.y * r1v.y;
    c1y += aw.x * r1v.y + aw.y * r1v.x;
    c2x += aw.x * r2v.x - aw.y * r2v.y;
    c2y += aw.x * r2v.y + aw.y * r2v.x;
  }
  or10re[bt * 64 + o] = ox;
  r256o[bt * 64 + o] = invL256 * (c1y - invL256 * c2x);
  float t0 = 0.f, t1 = 0.f, t2 = 0.f;
  for (int im = 0; im < 1024; im++) {
    float2 c = or2[(size_t)bt * 1024 + im];
    float px = ptr_re[(size_t)im * 64 + o], py = ptr_im[(size_t)im * 64 + o];
    t0 += c.x;
    t1 += c.x * px - c.y * py;
    float p2x = px * px - py * py, p2y = 2.f * px * py;
    t2 += c.x * p2x - c.y * p2y;
  }
  T1[bt * 64 + o] = t1; T2[bt * 64 + o] = t2;
  if (o == 0) T0[bt] = t0;
}

// ---------------- K4: G[k,o] = invL*C1 - invL^2*C2 (real P,Q; in place) ----------------
__global__ __launch_bounds__(256) void k4_or1(float2* __restrict__ alpha,
                                              const float* __restrict__ Pm, const float* __restrict__ Qm,
                                              const float* __restrict__ or10re, const float* __restrict__ r256o,
                                              const float* __restrict__ grd) {
  const int bt = blockIdx.x >> 2, xc = blockIdx.x & 3;
  const int x0 = xc * 64;
  __shared__ float aRe[64][68], aIm[64][68];
  const int tid = threadIdx.x;
  const float dt = grd[1] - grd[0];
  const float Ndt = 512.f * dt;
  float2* base = alpha + (size_t)bt * 16384;
  for (int idx = tid; idx < 4096; idx += 256) {
    int ii = idx >> 6, xl = idx & 63;
    float2 v = base[ii * 256 + x0 + xl];
    aRe[ii][xl] = v.x; aIm[ii][xl] = v.y;
  }
  __syncthreads();
  const int xq = tid & 15, oq = tid >> 4;
  const int xb = xq * 4, ob = oq * 4;
  float c1r[4][4] = {}, c1i[4][4] = {}, c2r[4][4] = {}, c2i[4][4] = {};
#pragma unroll 4
  for (int i = 0; i < 64; i++) {
    float4 ar = *(const float4*)&aRe[i][xb];
    float4 ai = *(const float4*)&aIm[i][xb];
    float4 pv = *(const float4*)&Pm[i * 64 + ob];
    float4 qv = *(const float4*)&Qm[i * 64 + ob];
    float pa[4] = {pv.x, pv.y, pv.z, pv.w};
    float qa[4] = {qv.x, qv.y, qv.z, qv.w};
    float arr[4] = {ar.x, ar.y, ar.z, ar.w};
    float aii[4] = {ai.x, ai.y, ai.z, ai.w};
#pragma unroll
    for (int a = 0; a < 4; a++) {
#pragma unroll
      for (int c = 0; c < 4; c++) {
        c1r[a][c] += arr[c] * pa[a];
        c1i[a][c] += aii[c] * pa[a];
        c2r[a][c] += arr[c] * qa[a];
        c2i[a][c] += aii[c] * qa[a];
      }
    }
  }
#pragma unroll
  for (int a = 0; a < 4; a++) {
    int o = ob + a;
    float2* orow = base + o * 256 + x0;
#pragma unroll
    for (int c = 0; c < 4; c++) {
      int gx = x0 + xb + c;
      float re, im;
      if (gx == 0) {
        re = or10re[bt * 64 + o];
        im = r256o[bt * 64 + o];
      } else {
        float invL = Ndt / (PI2F * (float)gx);
        re = invL * (c1i[a][c] - invL * c2r[a][c]);
        im = -invL * (c1r[a][c] + invL * c2i[a][c]);
      }
      orow[xb + c].x = re; orow[xb + c].y = im;
    }
  }
}

// ---------------- K5: zero-padded inverse transform + x2 epilogue ----------------
__global__ __launch_bounds__(64) void k5_ifft(const float2* __restrict__ G,
                                              float* __restrict__ x1,
                                              const float* __restrict__ T0, const float* __restrict__ T1,
                                              const float* __restrict__ T2, const float* __restrict__ grd) {
  __shared__ float2 bufA[512], bufB[512], tw[256];
  const int s = blockIdx.x, tid = threadIdx.x;
  const int bt = s >> 6;
  for (int m = tid; m < 256; m += 64) {
    float ang = PI2F * (float)m * (1.f / 512.f);
    float sv, cv; sincosf(ang, &sv, &cv);
    tw[m].x = cv; tw[m].y = sv;
  }
  const float2* src = G + (size_t)s * 256;
  float2 g0 = src[0];
  for (int k = tid; k < 512; k += 64) {
    float2 vv; vv.x = 0.f; vv.y = 0.f;
    if (k >= 1 && k < 256) vv = src[k];
    bufA[k] = vv;
  }
  __syncthreads();
  float2* sp = bufA; float2* dp = bufB;
  int Ns = 1;
  for (int st = 0; st < 9; st++) {
    const int shift = 8 - st;
    for (int jj = 0; jj < 4; jj++) {
      int j = tid + 64 * jj;
      int r = j & (Ns - 1);
      float2 a = sp[j], b = sp[j + 256];
      float2 w = tw[r << shift];
      float wbx = w.x * b.x - w.y * b.y;
      float wby = w.x * b.y + w.y * b.x;
      int id = ((j >> st) << (st + 1)) + r;
      dp[id].x = a.x + wbx; dp[id].y = a.y + wby;
      dp[id + Ns].x = a.x - wbx; dp[id + Ns].y = a.y - wby;
    }
    __syncthreads();
    float2* tp = sp; sp = dp; dp = tp;
    Ns <<= 1;
  }
  const float t0 = T0[bt], t1 = T1[s], t2 = T2[s];
  float* dst = x1 + (size_t)s * 512;
  for (int k = tid; k < 512; k += 64) {
    float g = grd[k];
    float sgn = (k & 1) ? -1.f : 1.f;
    dst[k] = (sp[k].x + g0.x + sgn * g0.y + t0 + t1 * g + 0.5f * t2 * g * g) * (1.f / 512.f);
  }
}

// ---------------- K6a: stats of x1 rows ----------------
__global__ __launch_bounds__(256) void k6a_stats(const float* __restrict__ x1,
                                                 float* __restrict__ mu2, float* __restrict__ rs2) {
  const int row = blockIdx.x * 4 + (threadIdx.x >> 6);
  const int lane = threadIdx.x & 63;
  const float* p = x1 + (size_t)row * 512;
  float s = 0.f, s2 = 0.f;
#pragma unroll
  for (int k = 0; k < 8; k++) { float v = p[lane + 64 * k]; s += v; s2 += v * v; }
#pragma unroll
  for (int off = 32; off; off >>= 1) { s += __shfl_down(s, off); s2 += __shfl_down(s2, off); }
  if (lane == 0) {
    float mu = s * (1.f / 512.f);
    float var = s2 * (1.f / 512.f) - mu * mu;
    mu2[row] = mu;
    rs2[row] = rsqrtf(var + 1e-5f);
  }
}

// ---------------- K6b: fused conv + norm + sin + transpose -> hseq ----------------
__global__ __launch_bounds__(256) void k6b_assemble(const float* __restrict__ xsraw,
                                                    const float* __restrict__ x1,
                                                    const float* __restrict__ conv_w,
                                                    const float* __restrict__ conv_b,
                                                    const float* __restrict__ mu2, const float* __restrict__ rs2,
                                                    float* __restrict__ hseq) {
  const int bt = blockIdx.x >> 2, nt4 = blockIdx.x & 3;
  const int b = bt >> 7, t = bt & 127;
  const int n0 = nt4 * 128;
  __shared__ float xt[128 * 66];      // aliased as tile[64*129] afterwards (8256 <= 8448)
  __shared__ float wt[64 * 66];
  __shared__ float mun[64], rsn[64];
  const int tid = threadIdx.x;
  for (int idx = tid; idx < 4096; idx += 256) {
    int o = idx >> 6, ii = idx & 63;
    wt[o * 66 + ii] = conv_w[idx];
  }
  if (tid < 64) { mun[tid] = mu2[bt * 64 + tid]; rsn[tid] = rs2[bt * 64 + tid]; }
  const float* src = xsraw + (size_t)bt * 32768;
  for (int idx = tid; idx < 8192; idx += 256) {
    int ii = idx >> 7, nl = idx & 127;
    xt[nl * 66 + ii] = src[ii * 512 + n0 + nl];
  }
  __syncthreads();
  const int lane = tid & 63, og = tid >> 6;
  float acc[2][16];
  for (int half = 0; half < 2; half++) {
    int nl = lane + 64 * half;
#pragma unroll
    for (int j = 0; j < 16; j++) acc[half][j] = conv_b[og * 16 + j];
    const float2* xrow = (const float2*)&xt[nl * 66];
#pragma unroll 4
    for (int i2 = 0; i2 < 32; i2++) {
      float2 v = xrow[i2];
#pragma unroll
      for (int j = 0; j < 16; j++) {
        float2 wv = *(const float2*)&wt[(og * 16 + j) * 66 + 2 * i2];
        acc[half][j] += wv.x * v.x + wv.y * v.y;
      }
    }
  }
  const float* xb = x1 + (size_t)bt * 32768 + n0;
  for (int half = 0; half < 2; half++) {
    int nl = lane + 64 * half;
#pragma unroll
    for (int j = 0; j < 16; j++) {
      int o = og * 16 + j;
      float v = (xb[o * 512 + nl] - mun[o]) * rsn[o] + acc[half][j];
      acc[half][j] = sinf(v);
    }
  }
  __syncthreads();          // all xt reads complete before aliasing
  float* tile = xt;
  for (int half = 0; half < 2; half++) {
    int nl = lane + 64 * half;
#pragma unroll
    for (int j = 0; j < 16; j++) tile[(og * 16 + j) * 129 + nl] = acc[half][j];
  }
  __syncthreads();
  for (int idx = tid; idx < 8192; idx += 256) {
    int nl = idx >> 6, o = idx & 63;
    hseq[(((size_t)(b * 512 + n0 + nl)) * 128 + t) * 64 + o] = tile[o * 129 + nl];
  }
}

// ---------------- K7: GRU v2 — one wave per sequence, weights in VGPRs, no barriers ----
__global__ __launch_bounds__(64) void k7_gru(const float* __restrict__ hseq,
                                             const float* __restrict__ Wx, const float* __restrict__ Wh,
                                             const float* __restrict__ bx, const float* __restrict__ bh,
                                             float* __restrict__ hist) {
  const int row = blockIdx.x;          // 0..2047
  const int j = threadIdx.x;           // 0..63
  float wxr[64], wxz[64], wxn[64], whr[64], whz[64], whn[64];
  {
    const float4* pr = (const float4*)(Wx + (size_t)j * 64);
    const float4* pz = (const float4*)(Wx + (size_t)(j + 64) * 64);
    const float4* pn = (const float4*)(Wx + (size_t)(j + 128) * 64);
    const float4* qr = (const float4*)(Wh + (size_t)j * 64);
    const float4* qz = (const float4*)(Wh + (size_t)(j + 64) * 64);
    const float4* qn = (const float4*)(Wh + (size_t)(j + 128) * 64);
#pragma unroll
    for (int c4 = 0; c4 < 16; c4++) {
      float4 v;
      v = pr[c4]; wxr[4*c4]=v.x; wxr[4*c4+1]=v.y; wxr[4*c4+2]=v.z; wxr[4*c4+3]=v.w;
      v = pz[c4]; wxz[4*c4]=v.x; wxz[4*c4+1]=v.y; wxz[4*c4+2]=v.z; wxz[4*c4+3]=v.w;
      v = pn[c4]; wxn[4*c4]=v.x; wxn[4*c4+1]=v.y; wxn[4*c4+2]=v.z; wxn[4*c4+3]=v.w;
      v = qr[c4]; whr[4*c4]=v.x; whr[4*c4+1]=v.y; whr[4*c4+2]=v.z; whr[4*c4+3]=v.w;
      v = qz[c4]; whz[4*c4]=v.x; whz[4*c4+1]=v.y; whz[4*c4+2]=v.z; whz[4*c4+3]=v.w;
      v = qn[c4]; whn[4*c4]=v.x; whn[4*c4+1]=v.y; whn[4*c4+2]=v.z; whn[4*c4+3]=v.w;
    }
  }
  const float br  = bx[j] + bh[j];
  const float bz  = bx[j + 64] + bh[j + 64];
  const float bxn = bx[j + 128];
  const float bhn = bh[j + 128];
  const float* xrow = hseq + (size_t)row * 8192;
  float* hrow = hist + (size_t)row * 8192;
  float h = 0.f;
  float xcur = xrow[j];
  for (int t = 0; t < 128; t++) {
    float xnext = (t < 127) ? xrow[(t + 1) * 64 + j] : 0.f;
    float aR = br, aZ = bz, aXN = bxn, aHN = bhn;
#pragma unroll
    for (int c = 0; c < 64; c++) {
      float hc = __shfl(h, c);
      float xc = __shfl(xcur, c);
      aR  += whr[c] * hc;
      aR  += wxr[c] * xc;
      aZ  += whz[c] * hc;
      aZ  += wxz[c] * xc;
      aXN += wxn[c] * xc;
      aHN += whn[c] * hc;
    }
    float r = 1.f / (1.f + __expf(-aR));
    float z = 1.f / (1.f + __expf(-aZ));
    float nv = aXN + r * aHN;
    float e2 = __expf(2.f * nv);
    float th = 1.f - 2.f / (e2 + 1.f);
    h = (1.f - z) * th + z * h;
    hrow[t * 64 + j] = h;
    xcur = xnext;
  }
}

// ---------------- K8: y = hist @ outW^T + outb ----------------
__global__ __launch_bounds__(256) void k8_out(const float* __restrict__ hist,
                                              const float* __restrict__ outW, const float* __restrict__ outb,
                                              float* __restrict__ y) {
  __shared__ float ht[64 * 68];
  __shared__ float wl[4096];
  const int tid = threadIdx.x;
  const int rt0 = blockIdx.x * 64;
  for (int idx = tid; idx < 4096; idx += 256) wl[idx] = outW[idx];
  for (int idx = tid; idx < 4096; idx += 256) {
    int rt = idx >> 6, c = idx & 63;
    ht[rt * 68 + c] = hist[(size_t)(rt0 + rt) * 64 + c];
  }
  __syncthreads();
  const int j = tid & 63, rg = tid >> 6;
  float wj[64];
#pragma unroll
  for (int c = 0; c < 64; c++) wj[c] = wl[j * 64 + c];
  const float bj = outb[j];
  for (int k = 0; k < 16; k++) {
    int rt = rg + 4 * k;
    float acc = bj;
    const float4* hp = (const float4*)&ht[rt * 68];
#pragma unroll
    for (int c4 = 0; c4 < 16; c4++) {
      float4 hv = hp[c4];
      acc += wj[4 * c4] * hv.x + wj[4 * c4 + 1] * hv.y + wj[4 * c4 + 2] * hv.z + wj[4 * c4 + 3] * hv.w;
    }
    y[(size_t)(rt0 + rt) * 64 + j] = acc;
  }
}

extern "C" void kernel_launch(void* const* d_in, const int* in_sizes, int n_in,
                              void* d_out, int out_size, void* d_ws, size_t ws_size,
                              hipStream_t stream) {
  (void)in_sizes; (void)n_in; (void)out_size;
  const float* x      = (const float*)d_in[0];
  const float* grd    = (const float*)d_in[1];
  const float* pre    = (const float*)d_in[2];
  const float* pim    = (const float*)d_in[3];
  const float* rre    = (const float*)d_in[4];
  const float* rim    = (const float*)d_in[5];
  const float* conv_w = (const float*)d_in[6];
  const float* conv_b = (const float*)d_in[7];
  const float* gWx    = (const float*)d_in[8];
  const float* gWh    = (const float*)d_in[9];
  const float* gbx    = (const float*)d_in[10];
  const float* gbh    = (const float*)d_in[11];
  const float* outW   = (const float*)d_in[12];
  const float* outb   = (const float*)d_in[13];
  float* out = (float*)d_out;
  float* ws  = (float*)d_ws;

  // total need: 52,003,328 floats = 198.4 MiB. Guard: clean fail (not crash) if short.
  if (ws_size < 52003328ULL * 4ULL) return;

  float*  XS = ws;                              // 16,777,216 f
  float2* AH = (float2*)(ws + 16777216);        // 8,388,608 c (half spectrum / G / later hseq)
  float*  X1 = ws + 33554432;                   // 16,777,216 f (x1, later hist)
  float*  sm = ws + 50331648;
  float2* A0    = (float2*)(sm + 0);
  float2* A256  = (float2*)(sm + 65536);
  float2* S1    = (float2*)(sm + 131072);
  float2* S2    = (float2*)(sm + 196608);
  float2* R0    = (float2*)(sm + 262144);
  float2* R1C   = (float2*)(sm + 270336);
  float2* R2C   = (float2*)(sm + 278528);
  float*  Pm    = sm + 286720;
  float*  Qm    = sm + 290816;
  float*  PTR   = sm + 294912;
  float*  PTI   = sm + 360448;
  float2* OR2   = (float2*)(sm + 425984);
  float*  T0    = sm + 1474560;
  float*  T1    = sm + 1475072;
  float*  T2    = sm + 1507840;
  float*  OR10R = sm + 1540608;
  float*  R256  = sm + 1573376;
  float*  MU2   = sm + 1606144;
  float*  RS2   = sm + 1638912;

  float* hseq = (float*)AH;   // reuse after K5 consumed G
  float* hist = X1;           // reuse after K6b consumed x1

  k1a_transpose<<<2048, 256, 0, stream>>>(x, XS);
  k2_fft<<<32768, 64, 0, stream>>>(XS, AH, A0, A256, S1, S2, grd);
  k3a_R<<<64, 64, 0, stream>>>(pre, pim, rre, rim, R0, R1C, R2C, Pm, Qm, PTR, PTI);
  k3b_or2<<<512, 1024, 0, stream>>>(pre, pim, rre, rim, A0, S1, S2, OR2);
  k3c_T<<<128, 256, 0, stream>>>(OR2, PTR, PTI, R0, R1C, R2C, A0, A256, T0, T1, T2, OR10R, R256, grd);
  k4_or1<<<2048, 256, 0, stream>>>(AH, Pm, Qm, OR10R, R256, grd);
  k5_ifft<<<32768, 64, 0, stream>>>(AH, X1, T0, T1, T2, grd);
  k6a_stats<<<8192, 256, 0, stream>>>(X1, MU2, RS2);
  k6b_assemble<<<2048, 256, 0, stream>>>(XS, X1, conv_w, conv_b, MU2, RS2, hseq);
  k7_gru<<<2048, 64, 0, stream>>>(hseq, gWx, gWh, gbx, gbh, hist);
  k8_out<<<4096, 256, 0, stream>>>(hist, outW, outb, out);
}

// Round 5
// 1234.907 us; speedup vs baseline: 1.2418x; 1.2418x over previous
//
#include <hip/hip_runtime.h>
#include <math.h>

#define PI2F 6.283185307179586f

// B=4 NX=512 NT=128 W=64 M=16 ; BT=512 ; NSIG=32768
// ws (floats): XS[16.7M] | AH half-spectrum (float2)[16.7M f] | X1/hist[16.7M] | smalls

// ---------------- K1a: transpose x[b,n,t,i] -> xs[bt,i,n] ----------------
__global__ __launch_bounds__(256) void k1a_transpose(const float* __restrict__ x,
                                                     float* __restrict__ xs) {
  const int bt = blockIdx.x >> 2, nt4 = blockIdx.x & 3;
  const int b = bt >> 7, t = bt & 127;
  const int n0 = nt4 * 128;
  __shared__ float tile[128 * 66];
  const int tid = threadIdx.x;
  const int i = tid & 63, nq = tid >> 6;
  const float* xb = x + (size_t)b * 4194304 + (size_t)t * 64;
  for (int k = 0; k < 32; k++) {
    int nl = nq + 4 * k;
    tile[nl * 66 + i] = xb[(size_t)(n0 + nl) * 8192 + i];
  }
  __syncthreads();
  float* dst = xs + (size_t)bt * 32768;
  for (int idx = tid; idx < 8192; idx += 256) {
    int ii = idx >> 7, nl = idx & 127;
    dst[ii * 512 + n0 + nl] = tile[nl * 66 + ii];
  }
}

// ---------------- K2: norm (inline) + forward FFT; write half spectrum ----------------
__global__ __launch_bounds__(64) void k2_fft(const float* __restrict__ xs,
                                             float2* __restrict__ alpha,   // [s][256]
                                             float2* __restrict__ a0,
                                             float2* __restrict__ a256,
                                             float2* __restrict__ s1o,
                                             float2* __restrict__ s2o,
                                             const float* __restrict__ grd) {
  __shared__ float2 bufA[512], bufB[512], tw[256];
  const int s = blockIdx.x, tid = threadIdx.x;
  const float dt = grd[1] - grd[0];
  const float Ndt = 512.f * dt;
  for (int m = tid; m < 256; m += 64) {
    float ang = -PI2F * (float)m * (1.f / 512.f);
    float sv, cv; sincosf(ang, &sv, &cv);
    tw[m].x = cv; tw[m].y = sv;
  }
  const float* src = xs + (size_t)s * 512;
  float v[8]; float sm = 0.f, sq = 0.f;
#pragma unroll
  for (int k = 0; k < 8; k++) { v[k] = src[tid + 64 * k]; sm += v[k]; sq += v[k] * v[k]; }
#pragma unroll
  for (int off = 32; off; off >>= 1) { sm += __shfl_down(sm, off); sq += __shfl_down(sq, off); }
  sm = __shfl(sm, 0); sq = __shfl(sq, 0);
  float mu = sm * (1.f / 512.f);
  float var = sq * (1.f / 512.f) - mu * mu;
  float rs = rsqrtf(var + 1e-5f);
#pragma unroll
  for (int k = 0; k < 8; k++) { bufA[tid + 64 * k].x = (v[k] - mu) * rs; bufA[tid + 64 * k].y = 0.f; }
  __syncthreads();
  float2* sp = bufA; float2* dp = bufB;
  int Ns = 1;
  for (int st = 0; st < 9; st++) {
    const int shift = 8 - st;
    for (int jj = 0; jj < 4; jj++) {
      int j = tid + 64 * jj;
      int r = j & (Ns - 1);
      float2 a = sp[j], b = sp[j + 256];
      float2 w = tw[r << shift];
      float wbx = w.x * b.x - w.y * b.y;
      float wby = w.x * b.y + w.y * b.x;
      int id = ((j >> st) << (st + 1)) + r;
      dp[id].x = a.x + wbx; dp[id].y = a.y + wby;
      dp[id + Ns].x = a.x - wbx; dp[id + Ns].y = a.y - wby;
    }
    __syncthreads();
    float2* tp = sp; sp = dp; dp = tp;
    Ns <<= 1;
  }
  float2* dst = alpha + (size_t)s * 256;
  float s1x = 0.f, s1y = 0.f, s2x = 0.f, s2y = 0.f;
  for (int k = tid; k < 512; k += 64) {
    float2 vv = sp[k];
    if (k < 256) dst[k] = vv;
    if (k != 0) {
      int kk = (k < 256) ? k : k - 512;
      float invL = Ndt / (PI2F * (float)kk);
      s1x += vv.y * invL; s1y -= vv.x * invL;
      float invL2 = invL * invL;
      s2x -= vv.x * invL2; s2y -= vv.y * invL2;
    }
  }
#pragma unroll
  for (int off = 32; off; off >>= 1) {
    s1x += __shfl_down(s1x, off); s1y += __shfl_down(s1y, off);
    s2x += __shfl_down(s2x, off); s2y += __shfl_down(s2y, off);
  }
  if (tid == 0) {
    s1o[s].x = s1x; s1o[s].y = s1y;
    s2o[s].x = s2x; s2o[s].y = s2y;
    a0[s] = sp[0];
    a256[s] = sp[256];
  }
}

// ---------------- K3a: R0/R1/R2 complex, P=2ReR1, Q=2ReR2, pole^T ----------------
__global__ __launch_bounds__(64) void k3a_R(const float* __restrict__ pre, const float* __restrict__ pim,
                                            const float* __restrict__ rre, const float* __restrict__ rim,
                                            float2* __restrict__ R0, float2* __restrict__ R1,
                                            float2* __restrict__ R2,
                                            float* __restrict__ Pm, float* __restrict__ Qm,
                                            float* __restrict__ ptr_re, float* __restrict__ ptr_im) {
  const int i = blockIdx.x, o = threadIdx.x;
  float r0x = 0, r0y = 0, r1x = 0, r1y = 0, r2x = 0, r2y = 0;
  for (int m = 0; m < 16; m++) {
    size_t idx = ((size_t)i * 64 + o) * 16 + m;
    float px = pre[idx], py = pim[idx];
    float rx = rre[idx], ry = rim[idx];
    r1x += rx; r1y += ry;
    r2x += rx * px - ry * py; r2y += rx * py + ry * px;
    float inv = 1.f / (px * px + py * py);
    r0x -= (rx * px + ry * py) * inv;
    r0y -= (ry * px - rx * py) * inv;
    ptr_re[((size_t)i * 16 + m) * 64 + o] = px;
    ptr_im[((size_t)i * 16 + m) * 64 + o] = py;
  }
  R0[i * 64 + o].x = r0x; R0[i * 64 + o].y = r0y;
  R1[i * 64 + o].x = r1x; R1[i * 64 + o].y = r1y;
  R2[i * 64 + o].x = r2x; R2[i * 64 + o].y = r2y;
  Pm[i * 64 + o] = 2.f * r1x;
  Qm[i * 64 + o] = 2.f * r2x;
}

// ---------------- K3b: or2[bt,o,m] ----------------
__global__ __launch_bounds__(1024) void k3b_or2(const float* __restrict__ pre, const float* __restrict__ pim,
                                                const float* __restrict__ rre, const float* __restrict__ rim,
                                                const float2* __restrict__ a0, const float2* __restrict__ s1,
                                                const float2* __restrict__ s2, float2* __restrict__ or2) {
  const int bt = blockIdx.x;
  __shared__ float2 A0[64], S1[64], S2[64];
  const int tid = threadIdx.x;
  if (tid < 64) { A0[tid] = a0[bt * 64 + tid]; S1[tid] = s1[bt * 64 + tid]; S2[tid] = s2[bt * 64 + tid]; }
  __syncthreads();
  float ax = 0.f, ay = 0.f;
  for (int i = 0; i < 64; i++) {
    size_t idx = (size_t)i * 1024 + tid;
    float px = pre[idx], py = pim[idx];
    float rx = rre[idx], ry = rim[idx];
    float inv = 1.f / (px * px + py * py);
    float q0x = -(rx * px + ry * py) * inv;
    float q0y = -(ry * px - rx * py) * inv;
    float2 a0v = A0[i], s1v = S1[i], s2v = S2[i];
    float tx = q0x * a0v.x - q0y * a0v.y + rx * s1v.x - ry * s1v.y;
    float ty = q0x * a0v.y + q0y * a0v.x + rx * s1v.y + ry * s1v.x;
    float rpx = rx * px - ry * py, rpy = rx * py + ry * px;
    tx += rpx * s2v.x - rpy * s2v.y;
    ty += rpx * s2v.y + rpy * s2v.x;
    ax -= tx; ay -= ty;
  }
  or2[(size_t)bt * 1024 + tid].x = ax;
  or2[(size_t)bt * 1024 + tid].y = ay;
}

// ---------------- K3c: T0/T1/T2 + or10re + r256 ----------------
__global__ __launch_bounds__(256) void k3c_T(const float2* __restrict__ or2,
                                             const float* __restrict__ ptr_re, const float* __restrict__ ptr_im,
                                             const float2* __restrict__ R0, const float2* __restrict__ R1,
                                             const float2* __restrict__ R2,
                                             const float2* __restrict__ a0, const float2* __restrict__ a256,
                                             float* __restrict__ T0, float* __restrict__ T1,
                                             float* __restrict__ T2,
                                             float* __restrict__ or10re, float* __restrict__ r256o,
                                             const float* __restrict__ grd) {
  const int bt = blockIdx.x * 4 + (threadIdx.x >> 6);
  const int o = threadIdx.x & 63;
  const float dt = grd[1] - grd[0];
  const float invL256 = -(512.f * dt) / (PI2F * 256.f);
  float ox = 0.f;
  float c1x = 0.f, c1y = 0.f, c2x = 0.f, c2y = 0.f;
  for (int i = 0; i < 64; i++) {
    float2 av = a0[bt * 64 + i];
    float2 rv = R0[i * 64 + o];
    ox += av.x * rv.x - av.y * rv.y;
    float2 aw = a256[bt * 64 + i];
    float2 r1v = R1[i * 64 + o], r2v = R2[i * 64 + o];
    c1x += aw.x * r1v.x - aw.y * r1v.y;
    c1y += aw.x * r1v.y + aw.y * r1v.x;
    c2x += aw.x * r2v.x - aw.y * r2v.y;
    c2y += aw.x * r2v.y + aw.y * r2v.x;
  }
  or10re[bt * 64 + o] = ox;
  r256o[bt * 64 + o] = invL256 * (c1y - invL256 * c2x);
  float t0 = 0.f, t1 = 0.f, t2 = 0.f;
  for (int im = 0; im < 1024; im++) {
    float2 c = or2[(size_t)bt * 1024 + im];
    float px = ptr_re[(size_t)im * 64 + o], py = ptr_im[(size_t)im * 64 + o];
    t0 += c.x;
    t1 += c.x * px - c.y * py;
    float p2x = px * px - py * py, p2y = 2.f * px * py;
    t2 += c.x * p2x - c.y * p2y;
  }
  T1[bt * 64 + o] = t1; T2[bt * 64 + o] = t2;
  if (o == 0) T0[bt] = t0;
}

// ---------------- K4: G[k,o] = invL*C1 - invL^2*C2 (real P,Q; in place) ----------------
__global__ __launch_bounds__(256) void k4_or1(float2* __restrict__ alpha,
                                              const float* __restrict__ Pm, const float* __restrict__ Qm,
                                              const float* __restrict__ or10re, const float* __restrict__ r256o,
                                              const float* __restrict__ grd) {
  const int bt = blockIdx.x >> 2, xc = blockIdx.x & 3;
  const int x0 = xc * 64;
  __shared__ float aRe[64][68], aIm[64][68];
  const int tid = threadIdx.x;
  const float dt = grd[1] - grd[0];
  const float Ndt = 512.f * dt;
  float2* base = alpha + (size_t)bt * 16384;
  for (int idx = tid; idx < 4096; idx += 256) {
    int ii = idx >> 6, xl = idx & 63;
    float2 v = base[ii * 256 + x0 + xl];
    aRe[ii][xl] = v.x; aIm[ii][xl] = v.y;
  }
  __syncthreads();
  const int xq = tid & 15, oq = tid >> 4;
  const int xb = xq * 4, ob = oq * 4;
  float c1r[4][4] = {}, c1i[4][4] = {}, c2r[4][4] = {}, c2i[4][4] = {};
#pragma unroll 4
  for (int i = 0; i < 64; i++) {
    float4 ar = *(const float4*)&aRe[i][xb];
    float4 ai = *(const float4*)&aIm[i][xb];
    float4 pv = *(const float4*)&Pm[i * 64 + ob];
    float4 qv = *(const float4*)&Qm[i * 64 + ob];
    float pa[4] = {pv.x, pv.y, pv.z, pv.w};
    float qa[4] = {qv.x, qv.y, qv.z, qv.w};
    float arr[4] = {ar.x, ar.y, ar.z, ar.w};
    float aii[4] = {ai.x, ai.y, ai.z, ai.w};
#pragma unroll
    for (int a = 0; a < 4; a++) {
#pragma unroll
      for (int c = 0; c < 4; c++) {
        c1r[a][c] += arr[c] * pa[a];
        c1i[a][c] += aii[c] * pa[a];
        c2r[a][c] += arr[c] * qa[a];
        c2i[a][c] += aii[c] * qa[a];
      }
    }
  }
#pragma unroll
  for (int a = 0; a < 4; a++) {
    int o = ob + a;
    float2* orow = base + o * 256 + x0;
#pragma unroll
    for (int c = 0; c < 4; c++) {
      int gx = x0 + xb + c;
      float re, im;
      if (gx == 0) {
        re = or10re[bt * 64 + o];
        im = r256o[bt * 64 + o];
      } else {
        float invL = Ndt / (PI2F * (float)gx);
        re = invL * (c1i[a][c] - invL * c2r[a][c]);
        im = -invL * (c1r[a][c] + invL * c2i[a][c]);
      }
      orow[xb + c].x = re; orow[xb + c].y = im;
    }
  }
}

// ---------------- K5: zero-padded inverse transform + x2 epilogue ----------------
__global__ __launch_bounds__(64) void k5_ifft(const float2* __restrict__ G,
                                              float* __restrict__ x1,
                                              const float* __restrict__ T0, const float* __restrict__ T1,
                                              const float* __restrict__ T2, const float* __restrict__ grd) {
  __shared__ float2 bufA[512], bufB[512], tw[256];
  const int s = blockIdx.x, tid = threadIdx.x;
  const int bt = s >> 6;
  for (int m = tid; m < 256; m += 64) {
    float ang = PI2F * (float)m * (1.f / 512.f);
    float sv, cv; sincosf(ang, &sv, &cv);
    tw[m].x = cv; tw[m].y = sv;
  }
  const float2* src = G + (size_t)s * 256;
  float2 g0 = src[0];
  for (int k = tid; k < 512; k += 64) {
    float2 vv; vv.x = 0.f; vv.y = 0.f;
    if (k >= 1 && k < 256) vv = src[k];
    bufA[k] = vv;
  }
  __syncthreads();
  float2* sp = bufA; float2* dp = bufB;
  int Ns = 1;
  for (int st = 0; st < 9; st++) {
    const int shift = 8 - st;
    for (int jj = 0; jj < 4; jj++) {
      int j = tid + 64 * jj;
      int r = j & (Ns - 1);
      float2 a = sp[j], b = sp[j + 256];
      float2 w = tw[r << shift];
      float wbx = w.x * b.x - w.y * b.y;
      float wby = w.x * b.y + w.y * b.x;
      int id = ((j >> st) << (st + 1)) + r;
      dp[id].x = a.x + wbx; dp[id].y = a.y + wby;
      dp[id + Ns].x = a.x - wbx; dp[id + Ns].y = a.y - wby;
    }
    __syncthreads();
    float2* tp = sp; sp = dp; dp = tp;
    Ns <<= 1;
  }
  const float t0 = T0[bt], t1 = T1[s], t2 = T2[s];
  float* dst = x1 + (size_t)s * 512;
  for (int k = tid; k < 512; k += 64) {
    float g = grd[k];
    float sgn = (k & 1) ? -1.f : 1.f;
    dst[k] = (sp[k].x + g0.x + sgn * g0.y + t0 + t1 * g + 0.5f * t2 * g * g) * (1.f / 512.f);
  }
}

// ---------------- K6a: stats of x1 rows ----------------
__global__ __launch_bounds__(256) void k6a_stats(const float* __restrict__ x1,
                                                 float* __restrict__ mu2, float* __restrict__ rs2) {
  const int row = blockIdx.x * 4 + (threadIdx.x >> 6);
  const int lane = threadIdx.x & 63;
  const float* p = x1 + (size_t)row * 512;
  float s = 0.f, s2 = 0.f;
#pragma unroll
  for (int k = 0; k < 8; k++) { float v = p[lane + 64 * k]; s += v; s2 += v * v; }
#pragma unroll
  for (int off = 32; off; off >>= 1) { s += __shfl_down(s, off); s2 += __shfl_down(s2, off); }
  if (lane == 0) {
    float mu = s * (1.f / 512.f);
    float var = s2 * (1.f / 512.f) - mu * mu;
    mu2[row] = mu;
    rs2[row] = rsqrtf(var + 1e-5f);
  }
}

// ---------------- K6b: fused conv + norm + sin + transpose -> hseq ----------------
__global__ __launch_bounds__(256) void k6b_assemble(const float* __restrict__ xsraw,
                                                    const float* __restrict__ x1,
                                                    const float* __restrict__ conv_w,
                                                    const float* __restrict__ conv_b,
                                                    const float* __restrict__ mu2, const float* __restrict__ rs2,
                                                    float* __restrict__ hseq) {
  const int bt = blockIdx.x >> 2, nt4 = blockIdx.x & 3;
  const int b = bt >> 7, t = bt & 127;
  const int n0 = nt4 * 128;
  __shared__ float xt[128 * 66];      // aliased as tile[64*129] afterwards (8256 <= 8448)
  __shared__ float wt[64 * 66];
  __shared__ float mun[64], rsn[64];
  const int tid = threadIdx.x;
  for (int idx = tid; idx < 4096; idx += 256) {
    int o = idx >> 6, ii = idx & 63;
    wt[o * 66 + ii] = conv_w[idx];
  }
  if (tid < 64) { mun[tid] = mu2[bt * 64 + tid]; rsn[tid] = rs2[bt * 64 + tid]; }
  const float* src = xsraw + (size_t)bt * 32768;
  for (int idx = tid; idx < 8192; idx += 256) {
    int ii = idx >> 7, nl = idx & 127;
    xt[nl * 66 + ii] = src[ii * 512 + n0 + nl];
  }
  __syncthreads();
  const int lane = tid & 63, og = tid >> 6;
  float acc[2][16];
  for (int half = 0; half < 2; half++) {
    int nl = lane + 64 * half;
#pragma unroll
    for (int j = 0; j < 16; j++) acc[half][j] = conv_b[og * 16 + j];
    const float2* xrow = (const float2*)&xt[nl * 66];
#pragma unroll 4
    for (int i2 = 0; i2 < 32; i2++) {
      float2 v = xrow[i2];
#pragma unroll
      for (int j = 0; j < 16; j++) {
        float2 wv = *(const float2*)&wt[(og * 16 + j) * 66 + 2 * i2];
        acc[half][j] += wv.x * v.x + wv.y * v.y;
      }
    }
  }
  const float* xb = x1 + (size_t)bt * 32768 + n0;
  for (int half = 0; half < 2; half++) {
    int nl = lane + 64 * half;
#pragma unroll
    for (int j = 0; j < 16; j++) {
      int o = og * 16 + j;
      float v = (xb[o * 512 + nl] - mun[o]) * rsn[o] + acc[half][j];
      acc[half][j] = sinf(v);
    }
  }
  __syncthreads();          // all xt reads complete before aliasing
  float* tile = xt;
  for (int half = 0; half < 2; half++) {
    int nl = lane + 64 * half;
#pragma unroll
    for (int j = 0; j < 16; j++) tile[(og * 16 + j) * 129 + nl] = acc[half][j];
  }
  __syncthreads();
  for (int idx = tid; idx < 8192; idx += 256) {
    int nl = idx >> 6, o = idx & 63;
    hseq[(((size_t)(b * 512 + n0 + nl)) * 128 + t) * 64 + o] = tile[o * 129 + nl];
  }
}

// ---------------- K7 v3: one wave/seq, weights in VGPRs (512-reg budget), LDS broadcast ----
__global__ __launch_bounds__(64, 1) void k7_gru(const float* __restrict__ hseq,
                                                const float* __restrict__ Wx, const float* __restrict__ Wh,
                                                const float* __restrict__ bx, const float* __restrict__ bh,
                                                float* __restrict__ hist) {
  __shared__ float hx[128];            // [0..63]=h, [64..127]=x
  const int row = blockIdx.x;          // 0..2047
  const int j = threadIdx.x;           // 0..63
  float wxr[64], wxz[64], wxn[64], whr[64], whz[64], whn[64];
  {
    const float4* pr = (const float4*)(Wx + (size_t)j * 64);
    const float4* pz = (const float4*)(Wx + (size_t)(j + 64) * 64);
    const float4* pn = (const float4*)(Wx + (size_t)(j + 128) * 64);
    const float4* qr = (const float4*)(Wh + (size_t)j * 64);
    const float4* qz = (const float4*)(Wh + (size_t)(j + 64) * 64);
    const float4* qn = (const float4*)(Wh + (size_t)(j + 128) * 64);
#pragma unroll
    for (int c4 = 0; c4 < 16; c4++) {
      float4 v;
      v = pr[c4]; wxr[4*c4]=v.x; wxr[4*c4+1]=v.y; wxr[4*c4+2]=v.z; wxr[4*c4+3]=v.w;
      v = pz[c4]; wxz[4*c4]=v.x; wxz[4*c4+1]=v.y; wxz[4*c4+2]=v.z; wxz[4*c4+3]=v.w;
      v = pn[c4]; wxn[4*c4]=v.x; wxn[4*c4+1]=v.y; wxn[4*c4+2]=v.z; wxn[4*c4+3]=v.w;
      v = qr[c4]; whr[4*c4]=v.x; whr[4*c4+1]=v.y; whr[4*c4+2]=v.z; whr[4*c4+3]=v.w;
      v = qz[c4]; whz[4*c4]=v.x; whz[4*c4+1]=v.y; whz[4*c4+2]=v.z; whz[4*c4+3]=v.w;
      v = qn[c4]; whn[4*c4]=v.x; whn[4*c4+1]=v.y; whn[4*c4+2]=v.z; whn[4*c4+3]=v.w;
    }
  }
  const float br  = bx[j] + bh[j];
  const float bz  = bx[j + 64] + bh[j + 64];
  const float bxn = bx[j + 128];
  const float bhn = bh[j + 128];
  const float* xrow = hseq + (size_t)row * 8192;
  float* hrow = hist + (size_t)row * 8192;
  float h = 0.f;
  float xcur = xrow[j];
  for (int t = 0; t < 128; t++) {
    float xnext = (t < 127) ? xrow[(t + 1) * 64 + j] : 0.f;
    __syncthreads();                   // WAR fence: prior step's reads done before overwrite
    hx[j] = h;
    hx[64 + j] = xcur;
    __syncthreads();
    float aR = br, aZ = bz, aXN = bxn, aHN = bhn;
#pragma unroll
    for (int c4 = 0; c4 < 16; c4++) {
      float4 hv = *(const float4*)&hx[c4 * 4];        // uniform addr -> broadcast
      float4 xv = *(const float4*)&hx[64 + c4 * 4];   // uniform addr -> broadcast
      aR  += whr[4*c4] * hv.x + whr[4*c4+1] * hv.y + whr[4*c4+2] * hv.z + whr[4*c4+3] * hv.w;
      aZ  += whz[4*c4] * hv.x + whz[4*c4+1] * hv.y + whz[4*c4+2] * hv.z + whz[4*c4+3] * hv.w;
      aHN += whn[4*c4] * hv.x + whn[4*c4+1] * hv.y + whn[4*c4+2] * hv.z + whn[4*c4+3] * hv.w;
      aR  += wxr[4*c4] * xv.x + wxr[4*c4+1] * xv.y + wxr[4*c4+2] * xv.z + wxr[4*c4+3] * xv.w;
      aZ  += wxz[4*c4] * xv.x + wxz[4*c4+1] * xv.y + wxz[4*c4+2] * xv.z + wxz[4*c4+3] * xv.w;
      aXN += wxn[4*c4] * xv.x + wxn[4*c4+1] * xv.y + wxn[4*c4+2] * xv.z + wxn[4*c4+3] * xv.w;
    }
    float r = 1.f / (1.f + __expf(-aR));
    float z = 1.f / (1.f + __expf(-aZ));
    float nv = aXN + r * aHN;
    float e2 = __expf(2.f * nv);
    float th = 1.f - 2.f / (e2 + 1.f);
    h = (1.f - z) * th + z * h;
    hrow[t * 64 + j] = h;
    xcur = xnext;
  }
}

// ---------------- K8: y = hist @ outW^T + outb ----------------
__global__ __launch_bounds__(256) void k8_out(const float* __restrict__ hist,
                                              const float* __restrict__ outW, const float* __restrict__ outb,
                                              float* __restrict__ y) {
  __shared__ float ht[64 * 68];
  __shared__ float wl[4096];
  const int tid = threadIdx.x;
  const int rt0 = blockIdx.x * 64;
  for (int idx = tid; idx < 4096; idx += 256) wl[idx] = outW[idx];
  for (int idx = tid; idx < 4096; idx += 256) {
    int rt = idx >> 6, c = idx & 63;
    ht[rt * 68 + c] = hist[(size_t)(rt0 + rt) * 64 + c];
  }
  __syncthreads();
  const int j = tid & 63, rg = tid >> 6;
  float wj[64];
#pragma unroll
  for (int c = 0; c < 64; c++) wj[c] = wl[j * 64 + c];
  const float bj = outb[j];
  for (int k = 0; k < 16; k++) {
    int rt = rg + 4 * k;
    float acc = bj;
    const float4* hp = (const float4*)&ht[rt * 68];
#pragma unroll
    for (int c4 = 0; c4 < 16; c4++) {
      float4 hv = hp[c4];
      acc += wj[4 * c4] * hv.x + wj[4 * c4 + 1] * hv.y + wj[4 * c4 + 2] * hv.z + wj[4 * c4 + 3] * hv.w;
    }
    y[(size_t)(rt0 + rt) * 64 + j] = acc;
  }
}

extern "C" void kernel_launch(void* const* d_in, const int* in_sizes, int n_in,
                              void* d_out, int out_size, void* d_ws, size_t ws_size,
                              hipStream_t stream) {
  (void)in_sizes; (void)n_in; (void)out_size;
  const float* x      = (const float*)d_in[0];
  const float* grd    = (const float*)d_in[1];
  const float* pre    = (const float*)d_in[2];
  const float* pim    = (const float*)d_in[3];
  const float* rre    = (const float*)d_in[4];
  const float* rim    = (const float*)d_in[5];
  const float* conv_w = (const float*)d_in[6];
  const float* conv_b = (const float*)d_in[7];
  const float* gWx    = (const float*)d_in[8];
  const float* gWh    = (const float*)d_in[9];
  const float* gbx    = (const float*)d_in[10];
  const float* gbh    = (const float*)d_in[11];
  const float* outW   = (const float*)d_in[12];
  const float* outb   = (const float*)d_in[13];
  float* out = (float*)d_out;
  float* ws  = (float*)d_ws;

  // total need: 52,003,328 floats = 198.4 MiB. Guard: clean fail (not crash) if short.
  if (ws_size < 52003328ULL * 4ULL) return;

  float*  XS = ws;                              // 16,777,216 f
  float2* AH = (float2*)(ws + 16777216);        // 8,388,608 c (half spectrum / G / later hseq)
  float*  X1 = ws + 33554432;                   // 16,777,216 f (x1, later hist)
  float*  sm = ws + 50331648;
  float2* A0    = (float2*)(sm + 0);
  float2* A256  = (float2*)(sm + 65536);
  float2* S1    = (float2*)(sm + 131072);
  float2* S2    = (float2*)(sm + 196608);
  float2* R0    = (float2*)(sm + 262144);
  float2* R1C   = (float2*)(sm + 270336);
  float2* R2C   = (float2*)(sm + 278528);
  float*  Pm    = sm + 286720;
  float*  Qm    = sm + 290816;
  float*  PTR   = sm + 294912;
  float*  PTI   = sm + 360448;
  float2* OR2   = (float2*)(sm + 425984);
  float*  T0    = sm + 1474560;
  float*  T1    = sm + 1475072;
  float*  T2    = sm + 1507840;
  float*  OR10R = sm + 1540608;
  float*  R256  = sm + 1573376;
  float*  MU2   = sm + 1606144;
  float*  RS2   = sm + 1638912;

  float* hseq = (float*)AH;   // reuse after K5 consumed G
  float* hist = X1;           // reuse after K6b consumed x1

  k1a_transpose<<<2048, 256, 0, stream>>>(x, XS);
  k2_fft<<<32768, 64, 0, stream>>>(XS, AH, A0, A256, S1, S2, grd);
  k3a_R<<<64, 64, 0, stream>>>(pre, pim, rre, rim, R0, R1C, R2C, Pm, Qm, PTR, PTI);
  k3b_or2<<<512, 1024, 0, stream>>>(pre, pim, rre, rim, A0, S1, S2, OR2);
  k3c_T<<<128, 256, 0, stream>>>(OR2, PTR, PTI, R0, R1C, R2C, A0, A256, T0, T1, T2, OR10R, R256, grd);
  k4_or1<<<2048, 256, 0, stream>>>(AH, Pm, Qm, OR10R, R256, grd);
  k5_ifft<<<32768, 64, 0, stream>>>(AH, X1, T0, T1, T2, grd);
  k6a_stats<<<8192, 256, 0, stream>>>(X1, MU2, RS2);
  k6b_assemble<<<2048, 256, 0, stream>>>(XS, X1, conv_w, conv_b, MU2, RS2, hseq);
  k7_gru<<<2048, 64, 0, stream>>>(hseq, gWx, gWh, gbx, gbh, hist);
  k8_out<<<4096, 256, 0, stream>>>(hist, outW, outb, out);
}

// Round 6
// 1178.012 us; speedup vs baseline: 1.3018x; 1.0483x over previous
//
#include <hip/hip_runtime.h>
#include <math.h>

#define PI2F 6.283185307179586f
typedef unsigned short ushort_t;

__device__ inline ushort_t f2bf(float f) {
  unsigned u = __float_as_uint(f);
  unsigned r = (u + 0x7FFFu + ((u >> 16) & 1u)) >> 16;
  return (ushort_t)r;
}
__device__ inline float bf2f(ushort_t u) {
  return __uint_as_float(((unsigned)u) << 16);
}

// B=4 NX=512 NT=128 W=64 M=16 ; BT=512 ; rows=2048 (GRU)
// ws (floats): XS[16.7M] | AH[16.7M] | X1[16.7M] | smalls
//  XS: xs_raw (k1a..k6b)  -> gxr,gxz bf16 (k6c..k7)
//  AH: alpha/G (k2..k5)   -> hseq bf16 [0..8.39M f) + gxn bf16 [8.39M..16.78M f)
//  X1: x1 (k5..k6b)       -> hist (k7..k8)

// ---------------- K1a: transpose x[b,n,t,i] -> xs[bt,i,n] ----------------
__global__ __launch_bounds__(256) void k1a_transpose(const float* __restrict__ x,
                                                     float* __restrict__ xs) {
  const int bt = blockIdx.x >> 2, nt4 = blockIdx.x & 3;
  const int b = bt >> 7, t = bt & 127;
  const int n0 = nt4 * 128;
  __shared__ float tile[128 * 66];
  const int tid = threadIdx.x;
  const int i = tid & 63, nq = tid >> 6;
  const float* xb = x + (size_t)b * 4194304 + (size_t)t * 64;
  for (int k = 0; k < 32; k++) {
    int nl = nq + 4 * k;
    tile[nl * 66 + i] = xb[(size_t)(n0 + nl) * 8192 + i];
  }
  __syncthreads();
  float* dst = xs + (size_t)bt * 32768;
  for (int idx = tid; idx < 8192; idx += 256) {
    int ii = idx >> 7, nl = idx & 127;
    dst[ii * 512 + n0 + nl] = tile[nl * 66 + ii];
  }
}

// ---------------- K2: norm (inline) + forward FFT; write half spectrum ----------------
__global__ __launch_bounds__(64) void k2_fft(const float* __restrict__ xs,
                                             float2* __restrict__ alpha,   // [s][256]
                                             float2* __restrict__ a0,
                                             float2* __restrict__ a256,
                                             float2* __restrict__ s1o,
                                             float2* __restrict__ s2o,
                                             const float* __restrict__ grd) {
  __shared__ float2 bufA[512], bufB[512], tw[256];
  const int s = blockIdx.x, tid = threadIdx.x;
  const float dt = grd[1] - grd[0];
  const float Ndt = 512.f * dt;
  for (int m = tid; m < 256; m += 64) {
    float ang = -PI2F * (float)m * (1.f / 512.f);
    float sv, cv; sincosf(ang, &sv, &cv);
    tw[m].x = cv; tw[m].y = sv;
  }
  const float* src = xs + (size_t)s * 512;
  float v[8]; float sm = 0.f, sq = 0.f;
#pragma unroll
  for (int k = 0; k < 8; k++) { v[k] = src[tid + 64 * k]; sm += v[k]; sq += v[k] * v[k]; }
#pragma unroll
  for (int off = 32; off; off >>= 1) { sm += __shfl_down(sm, off); sq += __shfl_down(sq, off); }
  sm = __shfl(sm, 0); sq = __shfl(sq, 0);
  float mu = sm * (1.f / 512.f);
  float var = sq * (1.f / 512.f) - mu * mu;
  float rs = rsqrtf(var + 1e-5f);
#pragma unroll
  for (int k = 0; k < 8; k++) { bufA[tid + 64 * k].x = (v[k] - mu) * rs; bufA[tid + 64 * k].y = 0.f; }
  __syncthreads();
  float2* sp = bufA; float2* dp = bufB;
  int Ns = 1;
  for (int st = 0; st < 9; st++) {
    const int shift = 8 - st;
    for (int jj = 0; jj < 4; jj++) {
      int j = tid + 64 * jj;
      int r = j & (Ns - 1);
      float2 a = sp[j], b = sp[j + 256];
      float2 w = tw[r << shift];
      float wbx = w.x * b.x - w.y * b.y;
      float wby = w.x * b.y + w.y * b.x;
      int id = ((j >> st) << (st + 1)) + r;
      dp[id].x = a.x + wbx; dp[id].y = a.y + wby;
      dp[id + Ns].x = a.x - wbx; dp[id + Ns].y = a.y - wby;
    }
    __syncthreads();
    float2* tp = sp; sp = dp; dp = tp;
    Ns <<= 1;
  }
  float2* dst = alpha + (size_t)s * 256;
  float s1x = 0.f, s1y = 0.f, s2x = 0.f, s2y = 0.f;
  for (int k = tid; k < 512; k += 64) {
    float2 vv = sp[k];
    if (k < 256) dst[k] = vv;
    if (k != 0) {
      int kk = (k < 256) ? k : k - 512;
      float invL = Ndt / (PI2F * (float)kk);
      s1x += vv.y * invL; s1y -= vv.x * invL;
      float invL2 = invL * invL;
      s2x -= vv.x * invL2; s2y -= vv.y * invL2;
    }
  }
#pragma unroll
  for (int off = 32; off; off >>= 1) {
    s1x += __shfl_down(s1x, off); s1y += __shfl_down(s1y, off);
    s2x += __shfl_down(s2x, off); s2y += __shfl_down(s2y, off);
  }
  if (tid == 0) {
    s1o[s].x = s1x; s1o[s].y = s1y;
    s2o[s].x = s2x; s2o[s].y = s2y;
    a0[s] = sp[0];
    a256[s] = sp[256];
  }
}

// ---------------- K3a: R0/R1/R2 complex, P=2ReR1, Q=2ReR2, pole^T ----------------
__global__ __launch_bounds__(64) void k3a_R(const float* __restrict__ pre, const float* __restrict__ pim,
                                            const float* __restrict__ rre, const float* __restrict__ rim,
                                            float2* __restrict__ R0, float2* __restrict__ R1,
                                            float2* __restrict__ R2,
                                            float* __restrict__ Pm, float* __restrict__ Qm,
                                            float* __restrict__ ptr_re, float* __restrict__ ptr_im) {
  const int i = blockIdx.x, o = threadIdx.x;
  float r0x = 0, r0y = 0, r1x = 0, r1y = 0, r2x = 0, r2y = 0;
  for (int m = 0; m < 16; m++) {
    size_t idx = ((size_t)i * 64 + o) * 16 + m;
    float px = pre[idx], py = pim[idx];
    float rx = rre[idx], ry = rim[idx];
    r1x += rx; r1y += ry;
    r2x += rx * px - ry * py; r2y += rx * py + ry * px;
    float inv = 1.f / (px * px + py * py);
    r0x -= (rx * px + ry * py) * inv;
    r0y -= (ry * px - rx * py) * inv;
    ptr_re[((size_t)i * 16 + m) * 64 + o] = px;
    ptr_im[((size_t)i * 16 + m) * 64 + o] = py;
  }
  R0[i * 64 + o].x = r0x; R0[i * 64 + o].y = r0y;
  R1[i * 64 + o].x = r1x; R1[i * 64 + o].y = r1y;
  R2[i * 64 + o].x = r2x; R2[i * 64 + o].y = r2y;
  Pm[i * 64 + o] = 2.f * r1x;
  Qm[i * 64 + o] = 2.f * r2x;
}

// ---------------- K3b: or2[bt,o,m] ----------------
__global__ __launch_bounds__(1024) void k3b_or2(const float* __restrict__ pre, const float* __restrict__ pim,
                                                const float* __restrict__ rre, const float* __restrict__ rim,
                                                const float2* __restrict__ a0, const float2* __restrict__ s1,
                                                const float2* __restrict__ s2, float2* __restrict__ or2) {
  const int bt = blockIdx.x;
  __shared__ float2 A0[64], S1[64], S2[64];
  const int tid = threadIdx.x;
  if (tid < 64) { A0[tid] = a0[bt * 64 + tid]; S1[tid] = s1[bt * 64 + tid]; S2[tid] = s2[bt * 64 + tid]; }
  __syncthreads();
  float ax = 0.f, ay = 0.f;
  for (int i = 0; i < 64; i++) {
    size_t idx = (size_t)i * 1024 + tid;
    float px = pre[idx], py = pim[idx];
    float rx = rre[idx], ry = rim[idx];
    float inv = 1.f / (px * px + py * py);
    float q0x = -(rx * px + ry * py) * inv;
    float q0y = -(ry * px - rx * py) * inv;
    float2 a0v = A0[i], s1v = S1[i], s2v = S2[i];
    float tx = q0x * a0v.x - q0y * a0v.y + rx * s1v.x - ry * s1v.y;
    float ty = q0x * a0v.y + q0y * a0v.x + rx * s1v.y + ry * s1v.x;
    float rpx = rx * px - ry * py, rpy = rx * py + ry * px;
    tx += rpx * s2v.x - rpy * s2v.y;
    ty += rpx * s2v.y + rpy * s2v.x;
    ax -= tx; ay -= ty;
  }
  or2[(size_t)bt * 1024 + tid].x = ax;
  or2[(size_t)bt * 1024 + tid].y = ay;
}

// ---------------- K3c: T0/T1/T2 + or10re + r256 ----------------
__global__ __launch_bounds__(256) void k3c_T(const float2* __restrict__ or2,
                                             const float* __restrict__ ptr_re, const float* __restrict__ ptr_im,
                                             const float2* __restrict__ R0, const float2* __restrict__ R1,
                                             const float2* __restrict__ R2,
                                             const float2* __restrict__ a0, const float2* __restrict__ a256,
                                             float* __restrict__ T0, float* __restrict__ T1,
                                             float* __restrict__ T2,
                                             float* __restrict__ or10re, float* __restrict__ r256o,
                                             const float* __restrict__ grd) {
  const int bt = blockIdx.x * 4 + (threadIdx.x >> 6);
  const int o = threadIdx.x & 63;
  const float dt = grd[1] - grd[0];
  const float invL256 = -(512.f * dt) / (PI2F * 256.f);
  float ox = 0.f;
  float c1x = 0.f, c1y = 0.f, c2x = 0.f, c2y = 0.f;
  for (int i = 0; i < 64; i++) {
    float2 av = a0[bt * 64 + i];
    float2 rv = R0[i * 64 + o];
    ox += av.x * rv.x - av.y * rv.y;
    float2 aw = a256[bt * 64 + i];
    float2 r1v = R1[i * 64 + o], r2v = R2[i * 64 + o];
    c1x += aw.x * r1v.x - aw.y * r1v.y;
    c1y += aw.x * r1v.y + aw.y * r1v.x;
    c2x += aw.x * r2v.x - aw.y * r2v.y;
    c2y += aw.x * r2v.y + aw.y * r2v.x;
  }
  or10re[bt * 64 + o] = ox;
  r256o[bt * 64 + o] = invL256 * (c1y - invL256 * c2x);
  float t0 = 0.f, t1 = 0.f, t2 = 0.f;
  for (int im = 0; im < 1024; im++) {
    float2 c = or2[(size_t)bt * 1024 + im];
    float px = ptr_re[(size_t)im * 64 + o], py = ptr_im[(size_t)im * 64 + o];
    t0 += c.x;
    t1 += c.x * px - c.y * py;
    float p2x = px * px - py * py, p2y = 2.f * px * py;
    t2 += c.x * p2x - c.y * p2y;
  }
  T1[bt * 64 + o] = t1; T2[bt * 64 + o] = t2;
  if (o == 0) T0[bt] = t0;
}

// ---------------- K4: G[k,o] = invL*C1 - invL^2*C2 (real P,Q; in place) ----------------
__global__ __launch_bounds__(256) void k4_or1(float2* __restrict__ alpha,
                                              const float* __restrict__ Pm, const float* __restrict__ Qm,
                                              const float* __restrict__ or10re, const float* __restrict__ r256o,
                                              const float* __restrict__ grd) {
  const int bt = blockIdx.x >> 2, xc = blockIdx.x & 3;
  const int x0 = xc * 64;
  __shared__ float aRe[64][68], aIm[64][68];
  const int tid = threadIdx.x;
  const float dt = grd[1] - grd[0];
  const float Ndt = 512.f * dt;
  float2* base = alpha + (size_t)bt * 16384;
  for (int idx = tid; idx < 4096; idx += 256) {
    int ii = idx >> 6, xl = idx & 63;
    float2 v = base[ii * 256 + x0 + xl];
    aRe[ii][xl] = v.x; aIm[ii][xl] = v.y;
  }
  __syncthreads();
  const int xq = tid & 15, oq = tid >> 4;
  const int xb = xq * 4, ob = oq * 4;
  float c1r[4][4] = {}, c1i[4][4] = {}, c2r[4][4] = {}, c2i[4][4] = {};
#pragma unroll 4
  for (int i = 0; i < 64; i++) {
    float4 ar = *(const float4*)&aRe[i][xb];
    float4 ai = *(const float4*)&aIm[i][xb];
    float4 pv = *(const float4*)&Pm[i * 64 + ob];
    float4 qv = *(const float4*)&Qm[i * 64 + ob];
    float pa[4] = {pv.x, pv.y, pv.z, pv.w};
    float qa[4] = {qv.x, qv.y, qv.z, qv.w};
    float arr[4] = {ar.x, ar.y, ar.z, ar.w};
    float aii[4] = {ai.x, ai.y, ai.z, ai.w};
#pragma unroll
    for (int a = 0; a < 4; a++) {
#pragma unroll
      for (int c = 0; c < 4; c++) {
        c1r[a][c] += arr[c] * pa[a];
        c1i[a][c] += aii[c] * pa[a];
        c2r[a][c] += arr[c] * qa[a];
        c2i[a][c] += aii[c] * qa[a];
      }
    }
  }
#pragma unroll
  for (int a = 0; a < 4; a++) {
    int o = ob + a;
    float2* orow = base + o * 256 + x0;
#pragma unroll
    for (int c = 0; c < 4; c++) {
      int gx = x0 + xb + c;
      float re, im;
      if (gx == 0) {
        re = or10re[bt * 64 + o];
        im = r256o[bt * 64 + o];
      } else {
        float invL = Ndt / (PI2F * (float)gx);
        re = invL * (c1i[a][c] - invL * c2r[a][c]);
        im = -invL * (c1r[a][c] + invL * c2i[a][c]);
      }
      orow[xb + c].x = re; orow[xb + c].y = im;
    }
  }
}

// ---------------- K5: zero-padded inverse transform + x2 epilogue ----------------
__global__ __launch_bounds__(64) void k5_ifft(const float2* __restrict__ G,
                                              float* __restrict__ x1,
                                              const float* __restrict__ T0, const float* __restrict__ T1,
                                              const float* __restrict__ T2, const float* __restrict__ grd) {
  __shared__ float2 bufA[512], bufB[512], tw[256];
  const int s = blockIdx.x, tid = threadIdx.x;
  const int bt = s >> 6;
  for (int m = tid; m < 256; m += 64) {
    float ang = PI2F * (float)m * (1.f / 512.f);
    float sv, cv; sincosf(ang, &sv, &cv);
    tw[m].x = cv; tw[m].y = sv;
  }
  const float2* src = G + (size_t)s * 256;
  float2 g0 = src[0];
  for (int k = tid; k < 512; k += 64) {
    float2 vv; vv.x = 0.f; vv.y = 0.f;
    if (k >= 1 && k < 256) vv = src[k];
    bufA[k] = vv;
  }
  __syncthreads();
  float2* sp = bufA; float2* dp = bufB;
  int Ns = 1;
  for (int st = 0; st < 9; st++) {
    const int shift = 8 - st;
    for (int jj = 0; jj < 4; jj++) {
      int j = tid + 64 * jj;
      int r = j & (Ns - 1);
      float2 a = sp[j], b = sp[j + 256];
      float2 w = tw[r << shift];
      float wbx = w.x * b.x - w.y * b.y;
      float wby = w.x * b.y + w.y * b.x;
      int id = ((j >> st) << (st + 1)) + r;
      dp[id].x = a.x + wbx; dp[id].y = a.y + wby;
      dp[id + Ns].x = a.x - wbx; dp[id + Ns].y = a.y - wby;
    }
    __syncthreads();
    float2* tp = sp; sp = dp; dp = tp;
    Ns <<= 1;
  }
  const float t0 = T0[bt], t1 = T1[s], t2 = T2[s];
  float* dst = x1 + (size_t)s * 512;
  for (int k = tid; k < 512; k += 64) {
    float g = grd[k];
    float sgn = (k & 1) ? -1.f : 1.f;
    dst[k] = (sp[k].x + g0.x + sgn * g0.y + t0 + t1 * g + 0.5f * t2 * g * g) * (1.f / 512.f);
  }
}

// ---------------- K6a: stats of x1 rows ----------------
__global__ __launch_bounds__(256) void k6a_stats(const float* __restrict__ x1,
                                                 float* __restrict__ mu2, float* __restrict__ rs2) {
  const int row = blockIdx.x * 4 + (threadIdx.x >> 6);
  const int lane = threadIdx.x & 63;
  const float* p = x1 + (size_t)row * 512;
  float s = 0.f, s2 = 0.f;
#pragma unroll
  for (int k = 0; k < 8; k++) { float v = p[lane + 64 * k]; s += v; s2 += v * v; }
#pragma unroll
  for (int off = 32; off; off >>= 1) { s += __shfl_down(s, off); s2 += __shfl_down(s2, off); }
  if (lane == 0) {
    float mu = s * (1.f / 512.f);
    float var = s2 * (1.f / 512.f) - mu * mu;
    mu2[row] = mu;
    rs2[row] = rsqrtf(var + 1e-5f);
  }
}

// ---------------- K6b: fused conv + norm + sin + transpose -> hseq (bf16) ----------------
__global__ __launch_bounds__(256) void k6b_assemble(const float* __restrict__ xsraw,
                                                    const float* __restrict__ x1,
                                                    const float* __restrict__ conv_w,
                                                    const float* __restrict__ conv_b,
                                                    const float* __restrict__ mu2, const float* __restrict__ rs2,
                                                    ushort_t* __restrict__ hseqb) {
  const int bt = blockIdx.x >> 2, nt4 = blockIdx.x & 3;
  const int b = bt >> 7, t = bt & 127;
  const int n0 = nt4 * 128;
  __shared__ float xt[128 * 66];      // aliased as tile[64*129] afterwards (8256 <= 8448)
  __shared__ float wt[64 * 66];
  __shared__ float mun[64], rsn[64];
  const int tid = threadIdx.x;
  for (int idx = tid; idx < 4096; idx += 256) {
    int o = idx >> 6, ii = idx & 63;
    wt[o * 66 + ii] = conv_w[idx];
  }
  if (tid < 64) { mun[tid] = mu2[bt * 64 + tid]; rsn[tid] = rs2[bt * 64 + tid]; }
  const float* src = xsraw + (size_t)bt * 32768;
  for (int idx = tid; idx < 8192; idx += 256) {
    int ii = idx >> 7, nl = idx & 127;
    xt[nl * 66 + ii] = src[ii * 512 + n0 + nl];
  }
  __syncthreads();
  const int lane = tid & 63, og = tid >> 6;
  float acc[2][16];
  for (int half = 0; half < 2; half++) {
    int nl = lane + 64 * half;
#pragma unroll
    for (int j = 0; j < 16; j++) acc[half][j] = conv_b[og * 16 + j];
    const float2* xrow = (const float2*)&xt[nl * 66];
#pragma unroll 4
    for (int i2 = 0; i2 < 32; i2++) {
      float2 v = xrow[i2];
#pragma unroll
      for (int j = 0; j < 16; j++) {
        float2 wv = *(const float2*)&wt[(og * 16 + j) * 66 + 2 * i2];
        acc[half][j] += wv.x * v.x + wv.y * v.y;
      }
    }
  }
  const float* xb = x1 + (size_t)bt * 32768 + n0;
  for (int half = 0; half < 2; half++) {
    int nl = lane + 64 * half;
#pragma unroll
    for (int j = 0; j < 16; j++) {
      int o = og * 16 + j;
      float v = (xb[o * 512 + nl] - mun[o]) * rsn[o] + acc[half][j];
      acc[half][j] = sinf(v);
    }
  }
  __syncthreads();          // all xt reads complete before aliasing
  float* tile = xt;
  for (int half = 0; half < 2; half++) {
    int nl = lane + 64 * half;
#pragma unroll
    for (int j = 0; j < 16; j++) tile[(og * 16 + j) * 129 + nl] = acc[half][j];
  }
  __syncthreads();
  for (int idx = tid; idx < 8192; idx += 256) {
    int nl = idx >> 6, o = idx & 63;
    hseqb[(((size_t)(b * 512 + n0 + nl)) * 128 + t) * 64 + o] = f2bf(tile[o * 129 + nl]);
  }
}

// ---------------- K6c: x-projection GEMM  gx = hseq @ Wx^T + bx  (bf16 out) ----------------
__global__ __launch_bounds__(256) void k6c_xgemm(const ushort_t* __restrict__ hseqb,
                                                 const float* __restrict__ Wx, const float* __restrict__ bxv,
                                                 ushort_t* __restrict__ gxr, ushort_t* __restrict__ gxz,
                                                 ushort_t* __restrict__ gxn) {
  __shared__ float ht[64][68];
  __shared__ float wt[192][66];
  const int tid = threadIdx.x;
  const size_t rt0 = (size_t)blockIdx.x * 64;
  for (int idx = tid; idx < 12288; idx += 256) {
    int g = idx >> 6, c = idx & 63;
    wt[g][c] = Wx[idx];
  }
  for (int idx = tid; idx < 4096; idx += 256) {
    int rt = idx >> 6, c = idx & 63;
    ht[rt][c] = bf2f(hseqb[(rt0 + rt) * 64 + c]);
  }
  __syncthreads();
  const int a = tid & 15, bq = tid >> 4;   // rows {a,a+16,a+32,a+48}, gates 12*bq..12*bq+11
  float acc[4][12];
#pragma unroll
  for (int g = 0; g < 12; g++) {
    float bv = bxv[bq * 12 + g];
    acc[0][g] = bv; acc[1][g] = bv; acc[2][g] = bv; acc[3][g] = bv;
  }
  for (int c4 = 0; c4 < 16; c4++) {
    float4 h0 = *(const float4*)&ht[a][c4 * 4];
    float4 h1 = *(const float4*)&ht[a + 16][c4 * 4];
    float4 h2 = *(const float4*)&ht[a + 32][c4 * 4];
    float4 h3 = *(const float4*)&ht[a + 48][c4 * 4];
#pragma unroll
    for (int g = 0; g < 12; g++) {
      float4 wv = *(const float4*)&wt[bq * 12 + g][c4 * 4];
      acc[0][g] += h0.x * wv.x + h0.y * wv.y + h0.z * wv.z + h0.w * wv.w;
      acc[1][g] += h1.x * wv.x + h1.y * wv.y + h1.z * wv.z + h1.w * wv.w;
      acc[2][g] += h2.x * wv.x + h2.y * wv.y + h2.z * wv.z + h2.w * wv.w;
      acc[3][g] += h3.x * wv.x + h3.y * wv.y + h3.z * wv.z + h3.w * wv.w;
    }
  }
#pragma unroll
  for (int r = 0; r < 4; r++) {
    size_t rt = rt0 + a + 16 * r;
#pragma unroll
    for (int g = 0; g < 12; g++) {
      int gg = bq * 12 + g;
      ushort_t v = f2bf(acc[r][g]);
      ushort_t* dst = (gg < 64) ? gxr : ((gg < 128) ? gxz : gxn);
      dst[rt * 64 + (gg & 63)] = v;
    }
  }
}

// ---------------- K7 v4: one wave/seq, only Wh in VGPRs (192), gx precomputed ----------------
__global__ __launch_bounds__(64, 2) void k7_gru(const ushort_t* __restrict__ gxr,
                                                const ushort_t* __restrict__ gxz,
                                                const ushort_t* __restrict__ gxn,
                                                const float* __restrict__ Wh,
                                                const float* __restrict__ bh,
                                                float* __restrict__ hist) {
  __shared__ float hx[64];
  const int row = blockIdx.x;          // 0..2047
  const int j = threadIdx.x;           // 0..63
  float whr[64], whz[64], whn[64];
  {
    const float4* qr = (const float4*)(Wh + (size_t)j * 64);
    const float4* qz = (const float4*)(Wh + (size_t)(j + 64) * 64);
    const float4* qn = (const float4*)(Wh + (size_t)(j + 128) * 64);
#pragma unroll
    for (int c4 = 0; c4 < 16; c4++) {
      float4 v;
      v = qr[c4]; whr[4*c4]=v.x; whr[4*c4+1]=v.y; whr[4*c4+2]=v.z; whr[4*c4+3]=v.w;
      v = qz[c4]; whz[4*c4]=v.x; whz[4*c4+1]=v.y; whz[4*c4+2]=v.z; whz[4*c4+3]=v.w;
      v = qn[c4]; whn[4*c4]=v.x; whn[4*c4+1]=v.y; whn[4*c4+2]=v.z; whn[4*c4+3]=v.w;
    }
  }
  const float bhr = bh[j], bhz = bh[j + 64], bhn = bh[j + 128];
  const ushort_t* gr = gxr + (size_t)row * 8192;
  const ushort_t* gz = gxz + (size_t)row * 8192;
  const ushort_t* gn = gxn + (size_t)row * 8192;
  float* hrow = hist + (size_t)row * 8192;
  float h = 0.f;
  for (int t = 0; t < 128; t++) {
    float xr = bf2f(gr[t * 64 + j]);
    float xz = bf2f(gz[t * 64 + j]);
    float xn = bf2f(gn[t * 64 + j]);
    __syncthreads();                   // WAR fence (1-wave workgroup: cheap)
    hx[j] = h;
    __syncthreads();
    float aR = bhr, aZ = bhz, aN = bhn;
#pragma unroll
    for (int c4 = 0; c4 < 16; c4++) {
      float4 hv = *(const float4*)&hx[c4 * 4];        // uniform addr -> broadcast
      aR += whr[4*c4] * hv.x + whr[4*c4+1] * hv.y + whr[4*c4+2] * hv.z + whr[4*c4+3] * hv.w;
      aZ += whz[4*c4] * hv.x + whz[4*c4+1] * hv.y + whz[4*c4+2] * hv.z + whz[4*c4+3] * hv.w;
      aN += whn[4*c4] * hv.x + whn[4*c4+1] * hv.y + whn[4*c4+2] * hv.z + whn[4*c4+3] * hv.w;
    }
    float r = 1.f / (1.f + __expf(-(xr + aR)));
    float z = 1.f / (1.f + __expf(-(xz + aZ)));
    float nv = xn + r * aN;
    float e2 = __expf(2.f * nv);
    float th = 1.f - 2.f / (e2 + 1.f);
    h = (1.f - z) * th + z * h;
    hrow[t * 64 + j] = h;
  }
}

// ---------------- K8: y = hist @ outW^T + outb ----------------
__global__ __launch_bounds__(256) void k8_out(const float* __restrict__ hist,
                                              const float* __restrict__ outW, const float* __restrict__ outb,
                                              float* __restrict__ y) {
  __shared__ float ht[64 * 68];
  __shared__ float wl[4096];
  const int tid = threadIdx.x;
  const int rt0 = blockIdx.x * 64;
  for (int idx = tid; idx < 4096; idx += 256) wl[idx] = outW[idx];
  for (int idx = tid; idx < 4096; idx += 256) {
    int rt = idx >> 6, c = idx & 63;
    ht[rt * 68 + c] = hist[(size_t)(rt0 + rt) * 64 + c];
  }
  __syncthreads();
  const int j = tid & 63, rg = tid >> 6;
  float wj[64];
#pragma unroll
  for (int c = 0; c < 64; c++) wj[c] = wl[j * 64 + c];
  const float bj = outb[j];
  for (int k = 0; k < 16; k++) {
    int rt = rg + 4 * k;
    float acc = bj;
    const float4* hp = (const float4*)&ht[rt * 68];
#pragma unroll
    for (int c4 = 0; c4 < 16; c4++) {
      float4 hv = hp[c4];
      acc += wj[4 * c4] * hv.x + wj[4 * c4 + 1] * hv.y + wj[4 * c4 + 2] * hv.z + wj[4 * c4 + 3] * hv.w;
    }
    y[(size_t)(rt0 + rt) * 64 + j] = acc;
  }
}

extern "C" void kernel_launch(void* const* d_in, const int* in_sizes, int n_in,
                              void* d_out, int out_size, void* d_ws, size_t ws_size,
                              hipStream_t stream) {
  (void)in_sizes; (void)n_in; (void)out_size;
  const float* x      = (const float*)d_in[0];
  const float* grd    = (const float*)d_in[1];
  const float* pre    = (const float*)d_in[2];
  const float* pim    = (const float*)d_in[3];
  const float* rre    = (const float*)d_in[4];
  const float* rim    = (const float*)d_in[5];
  const float* conv_w = (const float*)d_in[6];
  const float* conv_b = (const float*)d_in[7];
  const float* gWx    = (const float*)d_in[8];
  const float* gWh    = (const float*)d_in[9];
  const float* gbx    = (const float*)d_in[10];
  const float* gbh    = (const float*)d_in[11];
  const float* outW   = (const float*)d_in[12];
  const float* outb   = (const float*)d_in[13];
  float* out = (float*)d_out;
  float* ws  = (float*)d_ws;

  // total need: 52,003,328 floats = 198.4 MiB. Guard: clean fail (not crash) if short.
  if (ws_size < 52003328ULL * 4ULL) return;

  float*  XS = ws;                              // 16,777,216 f (xs_raw -> gxr,gxz bf16)
  float2* AH = (float2*)(ws + 16777216);        // 8,388,608 c  (alpha/G -> hseq bf16 + gxn bf16)
  float*  X1 = ws + 33554432;                   // 16,777,216 f (x1 -> hist)
  float*  sm = ws + 50331648;
  float2* A0    = (float2*)(sm + 0);
  float2* A256  = (float2*)(sm + 65536);
  float2* S1    = (float2*)(sm + 131072);
  float2* S2    = (float2*)(sm + 196608);
  float2* R0    = (float2*)(sm + 262144);
  float2* R1C   = (float2*)(sm + 270336);
  float2* R2C   = (float2*)(sm + 278528);
  float*  Pm    = sm + 286720;
  float*  Qm    = sm + 290816;
  float*  PTR   = sm + 294912;
  float*  PTI   = sm + 360448;
  float2* OR2   = (float2*)(sm + 425984);
  float*  T0    = sm + 1474560;
  float*  T1    = sm + 1475072;
  float*  T2    = sm + 1507840;
  float*  OR10R = sm + 1540608;
  float*  R256  = sm + 1573376;
  float*  MU2   = sm + 1606144;
  float*  RS2   = sm + 1638912;

  ushort_t* hseqb = (ushort_t*)AH;                  // 16,777,216 shorts (AH floats [0..8.39M))
  ushort_t* GXN   = (ushort_t*)AH + 16777216;       // 16,777,216 shorts (AH floats [8.39M..16.78M))
  ushort_t* GXR   = (ushort_t*)XS;                  // 16,777,216 shorts (XS floats [0..8.39M))
  ushort_t* GXZ   = (ushort_t*)XS + 16777216;       // 16,777,216 shorts (XS floats [8.39M..16.78M))
  float* hist = X1;                                 // reuse after k6b consumed x1

  k1a_transpose<<<2048, 256, 0, stream>>>(x, XS);
  k2_fft<<<32768, 64, 0, stream>>>(XS, AH, A0, A256, S1, S2, grd);
  k3a_R<<<64, 64, 0, stream>>>(pre, pim, rre, rim, R0, R1C, R2C, Pm, Qm, PTR, PTI);
  k3b_or2<<<512, 1024, 0, stream>>>(pre, pim, rre, rim, A0, S1, S2, OR2);
  k3c_T<<<128, 256, 0, stream>>>(OR2, PTR, PTI, R0, R1C, R2C, A0, A256, T0, T1, T2, OR10R, R256, grd);
  k4_or1<<<2048, 256, 0, stream>>>(AH, Pm, Qm, OR10R, R256, grd);
  k5_ifft<<<32768, 64, 0, stream>>>(AH, X1, T0, T1, T2, grd);
  k6a_stats<<<8192, 256, 0, stream>>>(X1, MU2, RS2);
  k6b_assemble<<<2048, 256, 0, stream>>>(XS, X1, conv_w, conv_b, MU2, RS2, hseqb);
  k6c_xgemm<<<4096, 256, 0, stream>>>(hseqb, gWx, gbx, GXR, GXZ, GXN);
  k7_gru<<<2048, 64, 0, stream>>>(GXR, GXZ, GXN, gWh, gbh, hist);
  k8_out<<<4096, 256, 0, stream>>>(hist, outW, outb, out);
}